// Round 1
// baseline (397.483 us; speedup 1.0000x reference)
//
#include <hip/hip_runtime.h>

// Problem constants
#define B_   8
#define S_   2048
#define HID_ 512
#define M_   (B_ * S_)   // 16384 rows
#define AW_  5           // window half-size

// ---------------------------------------------------------------------------
// 64x64-tile fp32 GEMM: C = [relu]( A(MxK) @ B(KxN) [+ bias(N)] )
// 256 threads, each computes a 4x4 micro-tile. BK=16.
// M%64==0, N%64==0, K%16==0 assumed (holds: 16384/512/512).
// ---------------------------------------------------------------------------
template <bool RELU, bool BIAS>
__global__ __launch_bounds__(256) void gemm64(const float* __restrict__ A,
                                              const float* __restrict__ Bm,
                                              const float* __restrict__ bias,
                                              float* __restrict__ C,
                                              int M, int N, int K) {
    __shared__ float As[16][68];  // [k][m], row stride 272B (16B aligned)
    __shared__ float Bs[16][68];  // [k][n]

    const int bm  = blockIdx.y * 64;
    const int bn  = blockIdx.x * 64;
    const int tid = threadIdx.x;
    const int tx  = tid & 15;   // 0..15 -> N
    const int ty  = tid >> 4;   // 0..15 -> M

    // A-tile load mapping: 64 rows x 16 k, 4 consecutive k per thread
    const int ar = tid >> 2;          // 0..63 row in tile
    const int ak = (tid & 3) << 2;    // 0,4,8,12
    // B-tile load mapping: 16 k-rows x 64 n, 4 consecutive n per thread
    const int br  = tid >> 4;         // 0..15 k-row
    const int bn4 = (tid & 15) << 2;  // 0..60

    float acc[4][4] = {};

    for (int k0 = 0; k0 < K; k0 += 16) {
        float4 av = *(const float4*)&A[(long)(bm + ar) * K + k0 + ak];
        As[ak + 0][ar] = av.x;
        As[ak + 1][ar] = av.y;
        As[ak + 2][ar] = av.z;
        As[ak + 3][ar] = av.w;
        float4 bv = *(const float4*)&Bm[(long)(k0 + br) * N + bn + bn4];
        *(float4*)&Bs[br][bn4] = bv;
        __syncthreads();

#pragma unroll
        for (int kk = 0; kk < 16; ++kk) {
            const float4 a4 = *(const float4*)&As[kk][ty * 4];
            const float4 b4 = *(const float4*)&Bs[kk][tx * 4];
            const float aa[4] = {a4.x, a4.y, a4.z, a4.w};
            const float bb[4] = {b4.x, b4.y, b4.z, b4.w};
#pragma unroll
            for (int i = 0; i < 4; ++i)
#pragma unroll
                for (int j = 0; j < 4; ++j)
                    acc[i][j] += aa[i] * bb[j];
        }
        __syncthreads();
    }

#pragma unroll
    for (int i = 0; i < 4; ++i) {
        const int row = bm + ty * 4 + i;
#pragma unroll
        for (int j = 0; j < 4; ++j) {
            const int col = bn + tx * 4 + j;
            float v = acc[i][j];
            if (BIAS) v += bias[col];
            if (RELU) v = fmaxf(v, 0.0f);
            C[(long)row * N + col] = v;
        }
    }
}

// ---------------------------------------------------------------------------
// hsum[b,s,:] = sum_{d=-5..5} h[b,s+d,:]  (zero outside [0,S) per batch)
// One float4 per thread over M_*HID_/4 elements.
// ---------------------------------------------------------------------------
__global__ __launch_bounds__(256) void winsum(const float* __restrict__ h,
                                              float* __restrict__ hs) {
    const int idx = blockIdx.x * blockDim.x + threadIdx.x;  // 0 .. M_*128-1
    const int c4 = idx & 127;        // HID_/4 = 128
    const int bs = idx >> 7;         // row 0..M_-1
    const int s  = bs & (S_ - 1);    // S_ = 2048 (pow2)

    float4 acc = {0.f, 0.f, 0.f, 0.f};
#pragma unroll
    for (int d = -AW_; d <= AW_; ++d) {
        const int ss = s + d;
        if (0 <= ss && ss < S_) {
            const float4 v = *(const float4*)&h[(long)(bs + d) * HID_ + (c4 << 2)];
            acc.x += v.x; acc.y += v.y; acc.z += v.z; acc.w += v.w;
        }
    }
    *(float4*)&hs[(long)bs * HID_ + (c4 << 2)] = acc;
}

// ---------------------------------------------------------------------------
// out[row, 0:2] = t[row, :] @ Wfc(512x2) + bfc   — one wave per row
// ---------------------------------------------------------------------------
__global__ __launch_bounds__(256) void fc_out(const float* __restrict__ t,
                                              const float* __restrict__ Wfc,
                                              const float* __restrict__ bfc,
                                              float* __restrict__ out) {
    const int row  = blockIdx.x * 4 + (threadIdx.x >> 6);
    const int lane = threadIdx.x & 63;

    float a0 = 0.f, a1 = 0.f;
    for (int i = lane; i < HID_; i += 64) {
        const float tv = t[(long)row * HID_ + i];
        a0 += tv * Wfc[i * 2 + 0];
        a1 += tv * Wfc[i * 2 + 1];
    }
#pragma unroll
    for (int off = 32; off > 0; off >>= 1) {
        a0 += __shfl_down(a0, off);
        a1 += __shfl_down(a1, off);
    }
    if (lane == 0) {
        out[row * 2 + 0] = a0 + bfc[0];
        out[row * 2 + 1] = a1 + bfc[1];
    }
}

// ---------------------------------------------------------------------------
extern "C" void kernel_launch(void* const* d_in, const int* in_sizes, int n_in,
                              void* d_out, int out_size, void* d_ws, size_t ws_size,
                              hipStream_t stream) {
    const float* x   = (const float*)d_in[0];
    const float* W1  = (const float*)d_in[1];
    const float* b1  = (const float*)d_in[2];
    // d_in[3] = Wq, d_in[4] = Wk : dead (softmax over singleton axis == 1.0)
    const float* Wv  = (const float*)d_in[5];
    const float* W2  = (const float*)d_in[6];
    const float* b2  = (const float*)d_in[7];
    const float* Wfc = (const float*)d_in[8];
    const float* bfc = (const float*)d_in[9];

    float* out_part = (float*)d_out;                    // 16384*2 floats
    float* aw_part  = (float*)d_out + (long)M_ * 2;     // 16384*512 floats (32MB)
    float* ws0      = (float*)d_ws;                     // 32MB scratch

    const dim3 ggrid(HID_ / 64, M_ / 64);  // (8, 256)
    const dim3 gblk(256);

    // 1) h = relu(x @ W1 + b1)          -> aw region (scratch use)
    gemm64<true, true><<<ggrid, gblk, 0, stream>>>(x, W1, b1, aw_part, M_, HID_, HID_);
    // 2) hsum = winsum11(h)             -> ws0
    winsum<<<(M_ * (HID_ / 4)) / 256, 256, 0, stream>>>(aw_part, ws0);
    // 3) aw = hsum @ Wv                 -> aw region (final output 2)
    gemm64<false, false><<<ggrid, gblk, 0, stream>>>(ws0, Wv, nullptr, aw_part, M_, HID_, HID_);
    // 4) t = relu(aw @ W2 + b2)         -> ws0
    gemm64<true, true><<<ggrid, gblk, 0, stream>>>(aw_part, W2, b2, ws0, M_, HID_, HID_);
    // 5) out = t @ Wfc + bfc            -> out region (final output 1)
    fc_out<<<M_ / 4, 256, 0, stream>>>(ws0, Wfc, bfc, out_part);
}

// Round 2
// 102.503 us; speedup vs baseline: 3.8778x; 3.8778x over previous
//
#include <hip/hip_runtime.h>
#include <stdint.h>

#define B_   8
#define S_   2048
#define HID_ 512
#define M_   (B_ * S_)   // 16384
#define AW_  5

typedef __attribute__((ext_vector_type(8))) short bf16x8;
typedef __attribute__((ext_vector_type(4))) float f32x4;

__device__ __forceinline__ unsigned short f2bf(float f) {
    uint32_t u = __builtin_bit_cast(uint32_t, f);
    u += 0x7FFFu + ((u >> 16) & 1u);   // RNE
    return (unsigned short)(u >> 16);
}
__device__ __forceinline__ float bf2f(unsigned short h) {
    uint32_t u = ((uint32_t)h) << 16;
    return __builtin_bit_cast(float, u);
}

// async global->LDS, 16B per lane (dest: wave-uniform base + lane*16, linear)
__device__ __forceinline__ void gload16(const void* g, void* l) {
    __builtin_amdgcn_global_load_lds(
        (const __attribute__((address_space(1))) void*)(uintptr_t)g,
        (__attribute__((address_space(3))) void*)(uint32_t)(uintptr_t)l,
        16, 0, 0);
}

// ---------------------------------------------------------------------------
// x (f32) -> xb (bf16), 8 elems/thread
// ---------------------------------------------------------------------------
__global__ __launch_bounds__(256) void conv_x(const float* __restrict__ x,
                                              unsigned short* __restrict__ xb) {
    const long i = (long)(blockIdx.x * 256 + threadIdx.x) * 8;
    const float4 a = *(const float4*)&x[i];
    const float4 b = *(const float4*)&x[i + 4];
    union { unsigned short u[8]; int4 v; } r;
    r.u[0] = f2bf(a.x); r.u[1] = f2bf(a.y); r.u[2] = f2bf(a.z); r.u[3] = f2bf(a.w);
    r.u[4] = f2bf(b.x); r.u[5] = f2bf(b.y); r.u[6] = f2bf(b.z); r.u[7] = f2bf(b.w);
    *(int4*)&xb[i] = r.v;
}

// ---------------------------------------------------------------------------
// W[k][n] f32 -> Wt[n][k] bf16 (512x512), LDS 32x32 tile transpose
// blockIdx.z selects which of the 3 weights
// ---------------------------------------------------------------------------
__global__ __launch_bounds__(256) void trans_w(const float* __restrict__ W1,
                                               const float* __restrict__ Wv,
                                               const float* __restrict__ W2,
                                               unsigned short* __restrict__ W1t,
                                               unsigned short* __restrict__ Wvt,
                                               unsigned short* __restrict__ W2t) {
    const float* src = blockIdx.z == 0 ? W1 : (blockIdx.z == 1 ? Wv : W2);
    unsigned short* dst = blockIdx.z == 0 ? W1t : (blockIdx.z == 1 ? Wvt : W2t);
    __shared__ float tile[32][33];
    const int k0 = blockIdx.y * 32, n0 = blockIdx.x * 32;
    const int tr = threadIdx.x >> 5, tc = threadIdx.x & 31;
#pragma unroll
    for (int p = 0; p < 4; ++p)
        tile[tr + p * 8][tc] = src[(long)(k0 + tr + p * 8) * HID_ + n0 + tc];
    __syncthreads();
#pragma unroll
    for (int p = 0; p < 4; ++p)
        dst[(long)(n0 + tr + p * 8) * HID_ + k0 + tc] = f2bf(tile[tc][tr + p * 8]);
}

// ---------------------------------------------------------------------------
// bf16 MFMA GEMM, m97 structure: 128x128 tile, BK=32, 4 waves (2x2), 16x16x32.
// A[M][512] bf16 row-major, Bt[N][K]=W^T bf16 row-major, C[M][512] bf16.
// ---------------------------------------------------------------------------
template <bool RELU, bool BIAS>
__global__ __launch_bounds__(256) void gemm_bf16(const unsigned short* __restrict__ A,
                                                 const unsigned short* __restrict__ Bt,
                                                 const float* __restrict__ bias,
                                                 unsigned short* __restrict__ C) {
    __shared__ __attribute__((aligned(16))) unsigned short As[128 * 32];
    __shared__ __attribute__((aligned(16))) unsigned short Bs[128 * 32];

    const int tid  = threadIdx.x;
    const long brow = (long)blockIdx.y * 128;
    const int  bn   = blockIdx.x * 128;

    const int w  = tid >> 6;
    const int l  = tid & 63;
    const int wm = (w >> 1) * 64;   // wave row offset in tile
    const int wn = (w & 1) * 64;    // wave col offset in tile
    const int lr = l & 15;          // fragment row/col index
    const int lk = (l >> 4) * 8;    // fragment k offset (elements)

    // staging: linear byte p -> LDS row p>>6 (64B rows), elem (p&63)>>1
    const int p0 = tid * 16;
    const int p1 = p0 + 4096;
    const unsigned short* a_src0 = A + (brow + (p0 >> 6)) * 512 + ((p0 & 63) >> 1);
    const unsigned short* a_src1 = A + (brow + (p1 >> 6)) * 512 + ((p1 & 63) >> 1);
    const unsigned short* b_src0 = Bt + (long)(bn + (p0 >> 6)) * 512 + ((p0 & 63) >> 1);
    const unsigned short* b_src1 = Bt + (long)(bn + (p1 >> 6)) * 512 + ((p1 & 63) >> 1);

    f32x4 acc[4][4];
#pragma unroll
    for (int i = 0; i < 4; ++i)
#pragma unroll
        for (int j = 0; j < 4; ++j) {
            f32x4 z = {0.f, 0.f, 0.f, 0.f};
            acc[i][j] = z;
        }

    for (int k0 = 0; k0 < 512; k0 += 32) {
        gload16(a_src0 + k0, &As[p0 >> 1]);
        gload16(a_src1 + k0, &As[p1 >> 1]);
        gload16(b_src0 + k0, &Bs[p0 >> 1]);
        gload16(b_src1 + k0, &Bs[p1 >> 1]);
        __syncthreads();   // compiler emits vmcnt(0) drain before barrier

        bf16x8 af[4], bfr[4];
#pragma unroll
        for (int i = 0; i < 4; ++i)
            af[i] = *(const bf16x8*)&As[(wm + i * 16 + lr) * 32 + lk];
#pragma unroll
        for (int j = 0; j < 4; ++j)
            bfr[j] = *(const bf16x8*)&Bs[(wn + j * 16 + lr) * 32 + lk];
#pragma unroll
        for (int i = 0; i < 4; ++i)
#pragma unroll
            for (int j = 0; j < 4; ++j)
                acc[i][j] = __builtin_amdgcn_mfma_f32_16x16x32_bf16(af[i], bfr[j],
                                                                    acc[i][j], 0, 0, 0);
        __syncthreads();
    }

    // epilogue: C/D layout col=lane&15, row=(lane>>4)*4+q
    float bv[4];
    if (BIAS) {
#pragma unroll
        for (int j = 0; j < 4; ++j) bv[j] = bias[bn + wn + j * 16 + lr];
    }
    const int rq = (l >> 4) * 4;
#pragma unroll
    for (int i = 0; i < 4; ++i)
#pragma unroll
        for (int q = 0; q < 4; ++q) {
            const long row = brow + wm + i * 16 + rq + q;
            unsigned short* crow = C + row * 512 + bn + wn + lr;
#pragma unroll
            for (int j = 0; j < 4; ++j) {
                float v = acc[i][j][q];
                if (BIAS) v += bv[j];
                if (RELU) v = fmaxf(v, 0.f);
                crow[j * 16] = f2bf(v);
            }
        }
}

// ---------------------------------------------------------------------------
// hsum[b,s,:] = sum_{d=-5..5} h[b,s+d,:]   bf16 in/out, f32 accum, 8 elems/thread
// ---------------------------------------------------------------------------
__global__ __launch_bounds__(256) void winsum(const unsigned short* __restrict__ h,
                                              unsigned short* __restrict__ hs) {
    const long idx = (long)blockIdx.x * 256 + threadIdx.x;
    const int  c8  = (int)(idx & 63);        // 512/8 = 64 chunks per row
    const long bs  = idx >> 6;
    const int  s   = (int)(bs & (S_ - 1));

    float acc[8] = {};
#pragma unroll
    for (int d = -AW_; d <= AW_; ++d) {
        const int ss = s + d;
        if (0 <= ss && ss < S_) {
            const int4 v = *(const int4*)&h[(bs + d) * HID_ + c8 * 8];
            const unsigned short* u = (const unsigned short*)&v;
#pragma unroll
            for (int e = 0; e < 8; ++e) acc[e] += bf2f(u[e]);
        }
    }
    union { unsigned short u[8]; int4 v; } r;
#pragma unroll
    for (int e = 0; e < 8; ++e) r.u[e] = f2bf(acc[e]);
    *(int4*)&hs[bs * HID_ + c8 * 8] = r.v;
}

// ---------------------------------------------------------------------------
// out[row,0:2] = t[row,:] @ Wfc + bfc — one wave per row, t is bf16
// ---------------------------------------------------------------------------
__global__ __launch_bounds__(256) void fc_out(const unsigned short* __restrict__ t,
                                              const float* __restrict__ Wfc,
                                              const float* __restrict__ bfc,
                                              float* __restrict__ out) {
    const int row  = blockIdx.x * 4 + (threadIdx.x >> 6);
    const int lane = threadIdx.x & 63;

    float a0 = 0.f, a1 = 0.f;
    for (int i = lane; i < HID_; i += 64) {
        const float tv = bf2f(t[(long)row * HID_ + i]);
        a0 += tv * Wfc[2 * i];
        a1 += tv * Wfc[2 * i + 1];
    }
#pragma unroll
    for (int off = 32; off > 0; off >>= 1) {
        a0 += __shfl_down(a0, off);
        a1 += __shfl_down(a1, off);
    }
    if (lane == 0) {
        out[row * 2 + 0] = a0 + bfc[0];
        out[row * 2 + 1] = a1 + bfc[1];
    }
}

// ---------------------------------------------------------------------------
// aw_bf (bf16) -> aw (f32) final output expand, 8 elems/thread
// ---------------------------------------------------------------------------
__global__ __launch_bounds__(256) void expand_aw(const unsigned short* __restrict__ awb,
                                                 float* __restrict__ aw) {
    const long i = (long)(blockIdx.x * 256 + threadIdx.x) * 8;
    const int4 v = *(const int4*)&awb[i];
    const unsigned short* u = (const unsigned short*)&v;
    float4 o0 = {bf2f(u[0]), bf2f(u[1]), bf2f(u[2]), bf2f(u[3])};
    float4 o1 = {bf2f(u[4]), bf2f(u[5]), bf2f(u[6]), bf2f(u[7])};
    *(float4*)&aw[i]     = o0;
    *(float4*)&aw[i + 4] = o1;
}

// ---------------------------------------------------------------------------
extern "C" void kernel_launch(void* const* d_in, const int* in_sizes, int n_in,
                              void* d_out, int out_size, void* d_ws, size_t ws_size,
                              hipStream_t stream) {
    const float* x   = (const float*)d_in[0];
    const float* W1  = (const float*)d_in[1];
    const float* b1  = (const float*)d_in[2];
    // d_in[3]=Wq, d_in[4]=Wk dead: softmax over singleton axis == 1.0
    const float* Wv  = (const float*)d_in[5];
    const float* W2  = (const float*)d_in[6];
    const float* b2  = (const float*)d_in[7];
    const float* Wfc = (const float*)d_in[8];
    const float* bfc = (const float*)d_in[9];

    float* out_part = (float*)d_out;                   // 16384*2 f32
    float* aw_f32   = (float*)d_out + (long)M_ * 2;    // 16384*512 f32 (32MB) "Q"

    // Q doubles as scratch until the final expand overwrites it:
    unsigned short* W1t = (unsigned short*)aw_f32;            // 512KB
    unsigned short* Wvt = W1t + 512 * 512;                    // 512KB
    unsigned short* W2t = Wvt + 512 * 512;                    // 512KB
    unsigned short* xb  = (unsigned short*)aw_f32 + 8388608;  // 16MB (2nd half of Q)

    // ws (>=32MB): two 16MB bf16 ping-pong buffers
    unsigned short* P0 = (unsigned short*)d_ws;          // h_bf, then aw_bf
    unsigned short* P1 = P0 + (long)M_ * HID_;           // hsum, then t_bf

    const dim3 gemm_grid(4, 128);  // N/128, M/128

    conv_x<<<4096, 256, 0, stream>>>(x, xb);
    trans_w<<<dim3(16, 16, 3), 256, 0, stream>>>(W1, Wv, W2, W1t, Wvt, W2t);
    // 1) h = relu(x @ W1 + b1)
    gemm_bf16<true, true><<<gemm_grid, 256, 0, stream>>>(xb, W1t, b1, P0);
    // 2) hsum = winsum11(h)
    winsum<<<4096, 256, 0, stream>>>(P0, P1);
    // 3) aw = hsum @ Wv  (bf16 copy; f32 expand at the end)
    gemm_bf16<false, false><<<gemm_grid, 256, 0, stream>>>(P1, Wvt, nullptr, P0);
    // 4) t = relu(aw @ W2 + b2)
    gemm_bf16<true, true><<<gemm_grid, 256, 0, stream>>>(P0, W2t, b2, P1);
    // 5) out = t @ Wfc + bfc
    fc_out<<<M_ / 4, 256, 0, stream>>>(P1, Wfc, bfc, out_part);
    // 6) aw f32 output (overwrites xb/Wt scratch in Q)
    expand_aw<<<4096, 256, 0, stream>>>(P0, aw_f32);
}

// Round 3
// 78.729 us; speedup vs baseline: 5.0487x; 1.3020x over previous
//
#include <hip/hip_runtime.h>
#include <stdint.h>

#define B_   8
#define S_   2048
#define HID_ 512
#define M_   (B_ * S_)   // 16384
#define AW_  5

typedef __attribute__((ext_vector_type(8))) short bf16x8;
typedef __attribute__((ext_vector_type(4))) float f32x4;
typedef unsigned short u16;

__device__ __forceinline__ u16 f2bf(float f) {
    uint32_t u = __builtin_bit_cast(uint32_t, f);
    u += 0x7FFFu + ((u >> 16) & 1u);   // RNE
    return (u16)(u >> 16);
}
__device__ __forceinline__ float bf2f(u16 h) {
    uint32_t u = ((uint32_t)h) << 16;
    return __builtin_bit_cast(float, u);
}

// async global->LDS, 16B/lane (dest = wave-uniform base + lane*16, linear)
__device__ __forceinline__ void gload16(const void* g, void* l) {
    __builtin_amdgcn_global_load_lds(
        (const __attribute__((address_space(1))) void*)(uintptr_t)g,
        (__attribute__((address_space(3))) void*)(uint32_t)(uintptr_t)l,
        16, 0, 0);
}

// ---------------------------------------------------------------------------
// x (f32) -> xb (bf16), 8 elems/thread
// ---------------------------------------------------------------------------
__global__ __launch_bounds__(256) void conv_x(const float* __restrict__ x,
                                              u16* __restrict__ xb) {
    const long i = (long)(blockIdx.x * 256 + threadIdx.x) * 8;
    const float4 a = *(const float4*)&x[i];
    const float4 b = *(const float4*)&x[i + 4];
    union { u16 u[8]; int4 v; } r;
    r.u[0] = f2bf(a.x); r.u[1] = f2bf(a.y); r.u[2] = f2bf(a.z); r.u[3] = f2bf(a.w);
    r.u[4] = f2bf(b.x); r.u[5] = f2bf(b.y); r.u[6] = f2bf(b.z); r.u[7] = f2bf(b.w);
    *(int4*)&xb[i] = r.v;
}

// ---------------------------------------------------------------------------
// W[k][n] f32 -> Wt[n][k] bf16 (512x512), LDS 32x32 tile transpose
// ---------------------------------------------------------------------------
__global__ __launch_bounds__(256) void trans_w(const float* __restrict__ W1,
                                               const float* __restrict__ Wv,
                                               const float* __restrict__ W2,
                                               u16* __restrict__ W1t,
                                               u16* __restrict__ Wvt,
                                               u16* __restrict__ W2t) {
    const float* src = blockIdx.z == 0 ? W1 : (blockIdx.z == 1 ? Wv : W2);
    u16* dst = blockIdx.z == 0 ? W1t : (blockIdx.z == 1 ? Wvt : W2t);
    __shared__ float tile[32][33];
    const int k0 = blockIdx.y * 32, n0 = blockIdx.x * 32;
    const int tr = threadIdx.x >> 5, tc = threadIdx.x & 31;
#pragma unroll
    for (int p = 0; p < 4; ++p)
        tile[tr + p * 8][tc] = src[(long)(k0 + tr + p * 8) * HID_ + n0 + tc];
    __syncthreads();
#pragma unroll
    for (int p = 0; p < 4; ++p)
        dst[(long)(n0 + tr + p * 8) * HID_ + k0 + tc] = f2bf(tile[tc][tr + p * 8]);
}

// ---------------------------------------------------------------------------
// bf16 MFMA GEMM: 128x128 tile, BK=64, double-buffered LDS, T2 XOR-swizzle,
// XCD-aware block swizzle. 4 waves (2x2), 16x16x32 MFMA, 4x4 frags/wave.
// A[M][512] bf16 row-major, Bt[N][K] bf16 row-major, C[M][512] bf16,
// optional Cf[M][512] f32 secondary output.
// LDS element (row, byte-col cb) lives at byte row*128 + (cb ^ ((row&7)<<4)).
// global_load_lds dest stays linear; the XOR is applied to the GLOBAL source
// (both-sides-or-neither, rule #21) and to the ds_read address.
// ---------------------------------------------------------------------------
template <bool RELU, bool BIAS, bool F32OUT>
__global__ __launch_bounds__(256, 2) void gemm_bf16(const u16* __restrict__ A,
                                                    const u16* __restrict__ Bt,
                                                    const float* __restrict__ bias,
                                                    u16* __restrict__ C,
                                                    float* __restrict__ Cf) {
    __shared__ __attribute__((aligned(16))) u16 As[2][128 * 64];  // 16KB x2
    __shared__ __attribute__((aligned(16))) u16 Bs[2][128 * 64];

    const int tid = threadIdx.x;
    // XCD swizzle: 512 blocks, 512%8==0 -> bijective simple form.
    const int bid = blockIdx.x;
    const int swz = (bid & 7) * 64 + (bid >> 3);
    const int  bn   = (swz & 3) * 128;
    const long brow = (long)(swz >> 2) * 128;

    const int w  = tid >> 6;
    const int l  = tid & 63;
    const int wm = (w >> 1) * 64;
    const int wn = (w & 1) * 64;
    const int lr  = l & 15;
    const int lkb = (l >> 4) * 16;        // fragment k-offset in BYTES
    const int sw  = (lr & 7) << 4;        // read-side swizzle (row&7 == lr&7)

    // staging: 4 gload16 per matrix per buffer; p = tid*16 + q*4096
    int pq[4];
    const u16* srcA[4];
    const u16* srcB[4];
#pragma unroll
    for (int q = 0; q < 4; ++q) {
        const int p   = tid * 16 + q * 4096;
        const int row = p >> 7;                         // 128B rows (64 bf16)
        const int cb  = (p & 127) ^ ((row & 7) << 4);   // inverse-swizzled src col
        pq[q]   = p;
        srcA[q] = A  + (brow + row) * 512 + (cb >> 1);
        srcB[q] = Bt + (long)(bn + row) * 512 + (cb >> 1);
    }

    f32x4 acc[4][4];
#pragma unroll
    for (int i = 0; i < 4; ++i)
#pragma unroll
        for (int j = 0; j < 4; ++j) {
            f32x4 z = {0.f, 0.f, 0.f, 0.f};
            acc[i][j] = z;
        }

#define STAGE(buf, k0)                                                   \
    {                                                                    \
        _Pragma("unroll") for (int q = 0; q < 4; ++q) {                  \
            gload16(srcA[q] + (k0), (char*)&As[buf][0] + pq[q]);         \
            gload16(srcB[q] + (k0), (char*)&Bs[buf][0] + pq[q]);         \
        }                                                                \
    }

    int cur = 0;
    STAGE(0, 0);
    __syncthreads();

    for (int t = 0; t < 8; ++t) {          // 8 K-tiles of 64
        if (t < 7) STAGE(cur ^ 1, (t + 1) * 64);
#pragma unroll
        for (int kk = 0; kk < 2; ++kk) {   // two 32-k sub-steps
            bf16x8 af[4], bfr[4];
#pragma unroll
            for (int i = 0; i < 4; ++i) {
                const int off = (wm + i * 16 + lr) * 128 + ((kk * 64 + lkb) ^ sw);
                af[i] = *(const bf16x8*)((const char*)&As[cur][0] + off);
            }
#pragma unroll
            for (int j = 0; j < 4; ++j) {
                const int off = (wn + j * 16 + lr) * 128 + ((kk * 64 + lkb) ^ sw);
                bfr[j] = *(const bf16x8*)((const char*)&Bs[cur][0] + off);
            }
#pragma unroll
            for (int i = 0; i < 4; ++i)
#pragma unroll
                for (int j = 0; j < 4; ++j)
                    acc[i][j] = __builtin_amdgcn_mfma_f32_16x16x32_bf16(
                        af[i], bfr[j], acc[i][j], 0, 0, 0);
        }
        __syncthreads();                   // drains vmcnt (stage) + lgkm
        cur ^= 1;
    }
#undef STAGE

    // epilogue: C/D layout col=lane&15, row=(lane>>4)*4+q
    float bv[4];
    if (BIAS) {
#pragma unroll
        for (int j = 0; j < 4; ++j) bv[j] = bias[bn + wn + j * 16 + lr];
    }
    const int rq = (l >> 4) * 4;
#pragma unroll
    for (int i = 0; i < 4; ++i)
#pragma unroll
        for (int q = 0; q < 4; ++q) {
            const long row = brow + wm + i * 16 + rq + q;
            u16*   crow = C + row * 512 + bn + wn + lr;
            float* frow = F32OUT ? (Cf + row * 512 + bn + wn + lr) : nullptr;
#pragma unroll
            for (int j = 0; j < 4; ++j) {
                float v = acc[i][j][q];
                if (BIAS) v += bv[j];
                if (RELU) v = fmaxf(v, 0.f);
                crow[j * 16] = f2bf(v);
                if (F32OUT) frow[j * 16] = v;
            }
        }
}

// ---------------------------------------------------------------------------
// hsum[b,s,:] = sum_{d=-5..5} h[b,s+d,:]   bf16 in/out, f32 accum
// ---------------------------------------------------------------------------
__global__ __launch_bounds__(256) void winsum(const u16* __restrict__ h,
                                              u16* __restrict__ hs) {
    const long idx = (long)blockIdx.x * 256 + threadIdx.x;
    const int  c8  = (int)(idx & 63);
    const long bs  = idx >> 6;
    const int  s   = (int)(bs & (S_ - 1));

    float acc[8] = {};
#pragma unroll
    for (int d = -AW_; d <= AW_; ++d) {
        const int ss = s + d;
        if (0 <= ss && ss < S_) {
            const int4 v = *(const int4*)&h[(bs + d) * HID_ + c8 * 8];
            const u16* u = (const u16*)&v;
#pragma unroll
            for (int e = 0; e < 8; ++e) acc[e] += bf2f(u[e]);
        }
    }
    union { u16 u[8]; int4 v; } r;
#pragma unroll
    for (int e = 0; e < 8; ++e) r.u[e] = f2bf(acc[e]);
    *(int4*)&hs[bs * HID_ + c8 * 8] = r.v;
}

// ---------------------------------------------------------------------------
// out[row,0:2] = t[row,:] @ Wfc + bfc — one wave per row
// ---------------------------------------------------------------------------
__global__ __launch_bounds__(256) void fc_out(const u16* __restrict__ t,
                                              const float* __restrict__ Wfc,
                                              const float* __restrict__ bfc,
                                              float* __restrict__ out) {
    const int row  = blockIdx.x * 4 + (threadIdx.x >> 6);
    const int lane = threadIdx.x & 63;

    float a0 = 0.f, a1 = 0.f;
    for (int i = lane; i < HID_; i += 64) {
        const float tv = bf2f(t[(long)row * HID_ + i]);
        a0 += tv * Wfc[2 * i];
        a1 += tv * Wfc[2 * i + 1];
    }
#pragma unroll
    for (int off = 32; off > 0; off >>= 1) {
        a0 += __shfl_down(a0, off);
        a1 += __shfl_down(a1, off);
    }
    if (lane == 0) {
        out[row * 2 + 0] = a0 + bfc[0];
        out[row * 2 + 1] = a1 + bfc[1];
    }
}

// ---------------------------------------------------------------------------
// fallback: aw_bf (bf16) -> aw (f32)
// ---------------------------------------------------------------------------
__global__ __launch_bounds__(256) void expand_aw(const u16* __restrict__ awb,
                                                 float* __restrict__ aw) {
    const long i = (long)(blockIdx.x * 256 + threadIdx.x) * 8;
    const int4 v = *(const int4*)&awb[i];
    const u16* u = (const u16*)&v;
    float4 o0 = {bf2f(u[0]), bf2f(u[1]), bf2f(u[2]), bf2f(u[3])};
    float4 o1 = {bf2f(u[4]), bf2f(u[5]), bf2f(u[6]), bf2f(u[7])};
    *(float4*)&aw[i]     = o0;
    *(float4*)&aw[i + 4] = o1;
}

// ---------------------------------------------------------------------------
extern "C" void kernel_launch(void* const* d_in, const int* in_sizes, int n_in,
                              void* d_out, int out_size, void* d_ws, size_t ws_size,
                              hipStream_t stream) {
    const float* x   = (const float*)d_in[0];
    const float* W1  = (const float*)d_in[1];
    const float* b1  = (const float*)d_in[2];
    // d_in[3]=Wq, d_in[4]=Wk dead: softmax over singleton axis == 1.0
    const float* Wv  = (const float*)d_in[5];
    const float* W2  = (const float*)d_in[6];
    const float* b2  = (const float*)d_in[7];
    const float* Wfc = (const float*)d_in[8];
    const float* bfc = (const float*)d_in[9];

    float* out_part = (float*)d_out;                 // 16384*2 f32
    float* aw_f32   = (float*)d_out + (long)M_ * 2;  // 16384*512 f32 (32MB) "Q"

    const size_t PEL = (size_t)M_ * HID_;            // elements per bf16 buffer
    unsigned char* ws = (unsigned char*)d_ws;

    // Q doubles as scratch until aw f32 is produced:
    u16* W1t = (u16*)aw_f32;                   // 512KB (dead after gemm1)
    u16* xb  = (u16*)aw_f32 + 8388608;         // 16MB  (dead after gemm1)

    // fused path needs Wvt/W2t outside Q (gemm3 overwrites all of Q with f32)
    const bool fuse = ws_size >= (size_t)(1 << 20) + 2 * PEL * sizeof(u16);
    u16 *Wvt, *W2t, *P0, *P1;
    if (fuse) {
        Wvt = (u16*)ws;                        // 512KB
        W2t = Wvt + 262144;                    // 512KB
        P0  = (u16*)(ws + (1 << 20));          // 16MB: h, then aw_bf
        P1  = P0 + PEL;                        // 16MB: hsum, then t
    } else {
        Wvt = W1t + 262144;
        W2t = Wvt + 262144;
        P0  = (u16*)ws;
        P1  = P0 + PEL;
    }

    conv_x<<<4096, 256, 0, stream>>>(x, xb);
    trans_w<<<dim3(16, 16, 3), 256, 0, stream>>>(W1, Wv, W2, W1t, Wvt, W2t);
    // 1) h = relu(x @ W1 + b1)
    gemm_bf16<true, true, false><<<512, 256, 0, stream>>>(xb, W1t, b1, P0, nullptr);
    // 2) hsum = winsum11(h)
    winsum<<<4096, 256, 0, stream>>>(P0, P1);
    // 3) aw = hsum @ Wv   (bf16 for gemm4 + f32 output when fused)
    if (fuse)
        gemm_bf16<false, false, true><<<512, 256, 0, stream>>>(P1, Wvt, nullptr, P0, aw_f32);
    else
        gemm_bf16<false, false, false><<<512, 256, 0, stream>>>(P1, Wvt, nullptr, P0, nullptr);
    // 4) t = relu(aw @ W2 + b2)
    gemm_bf16<true, true, false><<<512, 256, 0, stream>>>(P0, W2t, b2, P1, nullptr);
    // 5) out = t @ Wfc + bfc
    fc_out<<<M_ / 4, 256, 0, stream>>>(P1, Wfc, bfc, out_part);
    // 6) fallback expand
    if (!fuse)
        expand_aw<<<4096, 256, 0, stream>>>(P0, aw_f32);
}